// Round 1
// baseline (406.079 us; speedup 1.0000x reference)
//
#include <hip/hip_runtime.h>
#include <hip/hip_bf16.h>

typedef unsigned short u16;
typedef __bf16 bf16x8 __attribute__((ext_vector_type(8)));
typedef float f32x4 __attribute__((ext_vector_type(4)));

#define MDIM 16384   // 8 * 2048 rows of x
#define NDIM 2048    // output features
#define KDIM 2048    // input features
#define RANK 16
#define BM 128
#define BN 128
#define BK 32        // bf16 elements along K per stage (one 16x16x32 MFMA K-step)

// ---- fp32 -> bf16 round-to-nearest-even (bit-level, no header dependency) ----
__device__ __forceinline__ u16 f2bf(float f) {
    union { float f; unsigned u; } v; v.f = f;
    unsigned u = v.u;
    u += 0x7FFFu + ((u >> 16) & 1u);   // RNE
    return (u16)(u >> 16);
}

// ---- async global->LDS, 16B per lane, dest = uniform base + lane*16 ----
__device__ __forceinline__ void async_copy16(const void* gsrc, void* ldst) {
    __builtin_amdgcn_global_load_lds(
        (const __attribute__((address_space(1))) void*)gsrc,
        (__attribute__((address_space(3))) void*)ldst,
        16, 0, 0);
}

// ============================================================
// Kernel 1: x fp32 -> bf16 (float4 load, ushort4 store)
// ============================================================
__global__ __launch_bounds__(256) void xconv(const float* __restrict__ x,
                                             u16* __restrict__ xb) {
    int t = blockIdx.x * 256 + threadIdx.x;   // 0 .. MDIM*KDIM/4-1
    float4 v = ((const float4*)x)[t];
    ushort4 o;
    o.x = f2bf(v.x); o.y = f2bf(v.y); o.z = f2bf(v.z); o.w = f2bf(v.w);
    ((ushort4*)xb)[t] = o;
}

// ============================================================
// Kernel 2: w[o,d] = W[o,d] + 2 * sum_r B[o,r]*A[r,d]  -> bf16
// ============================================================
__global__ __launch_bounds__(256) void wprep(const float* __restrict__ W,
                                             const float* __restrict__ Bm,
                                             const float* __restrict__ Am,
                                             u16* __restrict__ wb) {
    int t = blockIdx.x * 256 + threadIdx.x;   // 0 .. NDIM*(KDIM/4)-1
    int o  = t >> 9;         // / (KDIM/4)
    int dq = t & 511;        // float4 index within row
    float4 acc = ((const float4*)W)[(size_t)o * (KDIM / 4) + dq];
    const float* Bo = Bm + (size_t)o * RANK;
#pragma unroll
    for (int r = 0; r < RANK; ++r) {
        float bv = 2.0f * Bo[r];   // ALPHA/RANK = 2
        float4 a4 = ((const float4*)(Am + (size_t)r * KDIM))[dq];
        acc.x += bv * a4.x; acc.y += bv * a4.y;
        acc.z += bv * a4.z; acc.w += bv * a4.w;
    }
    ushort4 ov;
    ov.x = f2bf(acc.x); ov.y = f2bf(acc.y); ov.z = f2bf(acc.z); ov.w = f2bf(acc.w);
    ((ushort4*)wb)[t] = ov;
}

// ============================================================
// Kernel 3: C[m,n] = sum_k xb[m,k]*wb[n,k] + bias[n]   (bf16 MFMA, fp32 out)
// m97 structure: 128x128 tile, 4 waves, 4x4 16x16x32 MFMA per wave,
// global_load_lds width=16, 2-barrier K-loop.
// ============================================================
__global__ __launch_bounds__(256) void gemm_bt(const u16* __restrict__ xb,
                                               const u16* __restrict__ wb,
                                               const float* __restrict__ bias,
                                               float* __restrict__ out) {
    __shared__ __align__(16) u16 As[BM * BK];   // [row][k], 64B rows
    __shared__ __align__(16) u16 Bs[BN * BK];

    const int tid  = threadIdx.x;
    const int lane = tid & 63;
    const int w    = tid >> 6;          // wave 0..3
    const int m0   = blockIdx.y * BM;
    const int n0   = blockIdx.x * BN;

    // staging: each wave issue covers 16 rows (64 lanes * 16B / 64B per row)
    const int srow  = lane >> 2;        // row within 16-row chunk
    const int selem = (lane & 3) * 8;   // element offset in row (8 bf16 = 16B)

    // wave sub-tile: 2x2 waves, each 64x64
    const int wr   = (w >> 1) * 64;
    const int wc   = (w & 1) * 64;
    const int quad = lane >> 4;
    const int l16  = lane & 15;

    int a_off[4], b_off[4];
#pragma unroll
    for (int i = 0; i < 4; ++i) {
        a_off[i] = (wr + i * 16 + l16) * BK + quad * 8;
        b_off[i] = (wc + i * 16 + l16) * BK + quad * 8;
    }

    f32x4 acc[4][4];
#pragma unroll
    for (int i = 0; i < 4; ++i)
#pragma unroll
        for (int j = 0; j < 4; ++j)
            acc[i][j] = (f32x4){0.f, 0.f, 0.f, 0.f};

    const u16* ga = xb + (size_t)m0 * KDIM;
    const u16* gb = wb + (size_t)n0 * KDIM;

    for (int k0 = 0; k0 < KDIM; k0 += BK) {
        // stage: wave w fills rows [w*32, w*32+32) of both tiles, 2 chunks of 16 rows
#pragma unroll
        for (int c = 0; c < 2; ++c) {
            const int rbase = w * 32 + c * 16;
            async_copy16(ga + (size_t)(rbase + srow) * KDIM + k0 + selem,
                         (char*)As + (size_t)rbase * (BK * 2));
            async_copy16(gb + (size_t)(rbase + srow) * KDIM + k0 + selem,
                         (char*)Bs + (size_t)rbase * (BK * 2));
        }
        __syncthreads();   // vmcnt(0) drain + barrier

        bf16x8 af[4], bfr[4];
#pragma unroll
        for (int i = 0; i < 4; ++i) af[i]  = *(const bf16x8*)(As + a_off[i]);
#pragma unroll
        for (int j = 0; j < 4; ++j) bfr[j] = *(const bf16x8*)(Bs + b_off[j]);

#pragma unroll
        for (int i = 0; i < 4; ++i)
#pragma unroll
            for (int j = 0; j < 4; ++j)
                acc[i][j] = __builtin_amdgcn_mfma_f32_16x16x32_bf16(
                    af[i], bfr[j], acc[i][j], 0, 0, 0);

        __syncthreads();   // protect LDS reuse next iteration
    }

    // epilogue: C/D layout col=lane&15, row=quad*4+reg
#pragma unroll
    for (int j = 0; j < 4; ++j) {
        const int col = n0 + wc + j * 16 + l16;
        const float bj = bias[col];
#pragma unroll
        for (int i = 0; i < 4; ++i) {
            const int rowb = m0 + wr + i * 16 + quad * 4;
#pragma unroll
            for (int r = 0; r < 4; ++r)
                out[(size_t)(rowb + r) * NDIM + col] = acc[i][j][r] + bj;
        }
    }
}

extern "C" void kernel_launch(void* const* d_in, const int* in_sizes, int n_in,
                              void* d_out, int out_size, void* d_ws, size_t ws_size,
                              hipStream_t stream) {
    const float* x    = (const float*)d_in[0];   // [8,2048,2048]
    const float* W    = (const float*)d_in[1];   // [2048,2048] row-major [o,d]
    const float* bias = (const float*)d_in[2];   // [2048]
    const float* Bm   = (const float*)d_in[3];   // [2048,16]
    const float* Am   = (const float*)d_in[4];   // [16,2048]
    float* out = (float*)d_out;

    u16* xb = (u16*)d_ws;                              // 16384*2048 bf16 = 64 MB
    u16* wbuf = xb + (size_t)MDIM * KDIM;              // 2048*2048 bf16 = 8 MB

    xconv<<<(MDIM * KDIM / 4) / 256, 256, 0, stream>>>(x, xb);
    wprep<<<(NDIM * (KDIM / 4)) / 256, 256, 0, stream>>>(W, Bm, Am, wbuf);

    dim3 grid(NDIM / BN, MDIM / BM);   // (16, 128)
    gemm_bt<<<grid, 256, 0, stream>>>(xb, wbuf, bias, out);
}